// Round 9
// baseline (673.183 us; speedup 1.0000x reference)
//
#include <hip/hip_runtime.h>

// GCN, bf16 Hs intermediate.
// Build: XCD-aware work-stealing bucket CSR — each block reads its real XCD id
// (HW_REG_XCC_ID) and claims chunks of its own stripe from per-stripe atomic
// counters (stealing other stripes when drained -> exact coverage). csr/cnt
// writes are then truly XCD-L2-local.
// 3x (X@W premul dinv -> bf16; pull-aggregate uint4 gathers); layer 3 fuses the
// mean-pool (LDS row accumulate, ~1 atomic row per block). Then classifier MLP.
constexpr int N = 100000;
constexpr int E = 1250000;
constexpr int G = 64;
constexpr int K = 32;            // bucket cap; P(deg>32)*N ~ 0.1, exact ovf path
constexpr int OVF_CAP = 65536;
constexpr int STRIPES = 8;
constexpr int NPS = N / STRIPES;              // 12500 nodes per stripe
constexpr int CHUNK = 2048;                   // edges per work unit
constexpr int CPS = (E + CHUNK - 1) / CHUNK;  // 611 chunks per stripe

__device__ inline unsigned bf16pack(float a, float b) {  // RNE, low=a high=b
  unsigned ua = __float_as_uint(a);
  ua = (ua + 0x7FFF + ((ua >> 16) & 1)) >> 16;
  unsigned ub = __float_as_uint(b);
  ub = (ub + 0x7FFF + ((ub >> 16) & 1)) & 0xFFFF0000u;
  return ua | ub;
}

// ---- XCD-aware work-stealing build -----------------------------------------
__global__ void build_kernel(const int* __restrict__ src, const int* __restrict__ dst,
                             int* __restrict__ cnt, int* __restrict__ csr,
                             int* __restrict__ ovf, int* __restrict__ ovf_cnt,
                             int* __restrict__ workctr) {
  __shared__ int s_chunk;
  unsigned xcc;
  asm volatile("s_getreg_b32 %0, hwreg(HW_REG_XCC_ID)" : "=s"(xcc));
  xcc &= (STRIPES - 1);
  for (int oi = 0; oi < STRIPES; oi++) {
    int st = (xcc + oi) & (STRIPES - 1);
    int lo = st * NPS, hi = lo + NPS;
    while (true) {
      if (threadIdx.x == 0) s_chunk = atomicAdd(&workctr[st], 1);
      __syncthreads();
      int c = s_chunk;
      __syncthreads();
      if (c >= CPS) break;
      int base = c * CHUNK + threadIdx.x * 8;
      auto process = [&](int s, int d) {
        if (d >= lo && d < hi) {
          int slot = atomicAdd(&cnt[d], 1);
          if (slot < K) {
            csr[d * K + slot] = s;
          } else {
            int q = atomicAdd(ovf_cnt, 1);
            if (q < OVF_CAP) { ovf[2 * q] = s; ovf[2 * q + 1] = d; }
          }
        }
      };
#pragma unroll
      for (int h = 0; h < 2; h++, base += 4) {
        if (base + 3 < E) {
          int4 s4 = *(const int4*)(src + base);
          int4 d4 = *(const int4*)(dst + base);
          process(s4.x, d4.x); process(s4.y, d4.y);
          process(s4.z, d4.z); process(s4.w, d4.w);
        } else {
          for (int j = 0; j < 4; j++)
            if (base + j < E) process(src[base + j], dst[base + j]);
        }
      }
    }
  }
}

// ---- Hs(bf16) = (X @ W) * dinv[row], 32 rows/block -------------------------
constexpr int XS_STRIDE = 68;
__global__ void gemm_premul_kernel(const float* __restrict__ X, const float* __restrict__ W,
                                   const int* __restrict__ cnt, unsigned* __restrict__ Hs2) {
  __shared__ float Ws[64 * 64];
  __shared__ float Xs[32 * XS_STRIDE];
  int tid = threadIdx.x;
  const float4* W4 = (const float4*)W;
#pragma unroll
  for (int j = 0; j < 4; j++)
    ((float4*)Ws)[tid + j * 256] = W4[tid + j * 256];
  int row0 = blockIdx.x * 32;
  const float4* X4 = (const float4*)(X + row0 * 64);
#pragma unroll
  for (int j = 0; j < 2; j++) {
    int idx = tid + j * 256;
    int r = idx >> 4, q = idx & 15;
    *((float4*)&Xs[r * XS_STRIDE + q * 4]) = X4[idx];
  }
  __syncthreads();
  int r0 = tid >> 4;
  int c = (tid & 15) * 4;
  float4 acc0 = {0, 0, 0, 0}, acc1 = {0, 0, 0, 0};
#pragma unroll
  for (int k = 0; k < 64; k++) {
    float4 w = *((const float4*)&Ws[k * 64 + c]);
    float xa = Xs[r0 * XS_STRIDE + k];
    float xb = Xs[(r0 + 16) * XS_STRIDE + k];
    acc0.x += xa * w.x; acc0.y += xa * w.y; acc0.z += xa * w.z; acc0.w += xa * w.w;
    acc1.x += xb * w.x; acc1.y += xb * w.y; acc1.z += xb * w.z; acc1.w += xb * w.w;
  }
  int ra = row0 + r0, rb = ra + 16;
  float da = rsqrtf((float)cnt[ra] + 1.0f);
  float db = rsqrtf((float)cnt[rb] + 1.0f);
  uint2 pa = make_uint2(bf16pack(acc0.x * da, acc0.y * da), bf16pack(acc0.z * da, acc0.w * da));
  uint2 pb = make_uint2(bf16pack(acc1.x * db, acc1.y * db), bf16pack(acc1.z * db, acc1.w * db));
  ((uint2*)Hs2)[ra * 16 + (tid & 15)] = pa;
  ((uint2*)Hs2)[rb * 16 + (tid & 15)] = pb;
}

// Shared gather core: acc[0..7] hold full channel sums after butterfly.
// lane = 8*g + i; group g handles edge k+g, lane covers bf16 channels 8i..8i+7.
__device__ inline void gather_rows(const unsigned* __restrict__ Hs2, int node, int m,
                                   int g, int i, int sv,
                                   const int* __restrict__ ovf, int on,
                                   float acc[8]) {
  const uint4* H4 = (const uint4*)Hs2;
#pragma unroll
  for (int t = 0; t < 8; t++) acc[t] = 0.f;
  for (int k = 0; k < m; k += 8) {
    int j = k + g;
    int s = __shfl(sv, j);
    bool valid = j < m;
    uint4 h = H4[(valid ? s : node) * 8 + i];
    if (valid) {
      acc[0] += __uint_as_float(h.x << 16); acc[1] += __uint_as_float(h.x & 0xFFFF0000u);
      acc[2] += __uint_as_float(h.y << 16); acc[3] += __uint_as_float(h.y & 0xFFFF0000u);
      acc[4] += __uint_as_float(h.z << 16); acc[5] += __uint_as_float(h.z & 0xFFFF0000u);
      acc[6] += __uint_as_float(h.w << 16); acc[7] += __uint_as_float(h.w & 0xFFFF0000u);
    }
  }
  if (on > 0 && g == 0) {                  // exact rare path (deg > K)
    for (int j = 0; j < on; j++)
      if (ovf[2 * j + 1] == node) {
        uint4 h = H4[ovf[2 * j] * 8 + i];
        acc[0] += __uint_as_float(h.x << 16); acc[1] += __uint_as_float(h.x & 0xFFFF0000u);
        acc[2] += __uint_as_float(h.y << 16); acc[3] += __uint_as_float(h.y & 0xFFFF0000u);
        acc[4] += __uint_as_float(h.z << 16); acc[5] += __uint_as_float(h.z & 0xFFFF0000u);
        acc[6] += __uint_as_float(h.w << 16); acc[7] += __uint_as_float(h.w & 0xFFFF0000u);
      }
  }
#pragma unroll
  for (int off = 8; off < 64; off <<= 1) {
#pragma unroll
    for (int t = 0; t < 8; t++) acc[t] += __shfl_xor(acc[t], off);
  }
}

// ---- layers 1,2: aggregate -> fp32 Xout ------------------------------------
__global__ void agg_kernel(const unsigned* __restrict__ Hs2, const int* __restrict__ cnt,
                           const int* __restrict__ csr, const int* __restrict__ ovf,
                           const int* __restrict__ ovf_cnt, const float* __restrict__ b,
                           float* __restrict__ Xout) {
  int stripe = blockIdx.x & (STRIPES - 1);
  int node = stripe * NPS + (blockIdx.x >> 3) * 4 + (threadIdx.x >> 6);
  int lane = threadIdx.x & 63;
  int g = lane >> 3, i = lane & 7;
  int c = cnt[node];
  int m = min(c, K);
  int sv = (lane < m) ? csr[node * K + lane] : node;
  float acc[8];
  gather_rows(Hs2, node, m, g, i, sv, ovf, min(*ovf_cnt, OVF_CAP), acc);
  if (g == 0) {
    uint4 hs = ((const uint4*)Hs2)[node * 8 + i];
    float di = rsqrtf((float)c + 1.0f);
    const float4* b4 = (const float4*)b;
    float4 blo = b4[2 * i], bhi = b4[2 * i + 1];
    float4 o0, o1;
    o0.x = fmaxf(di * (acc[0] + __uint_as_float(hs.x << 16)) + blo.x, 0.f);
    o0.y = fmaxf(di * (acc[1] + __uint_as_float(hs.x & 0xFFFF0000u)) + blo.y, 0.f);
    o0.z = fmaxf(di * (acc[2] + __uint_as_float(hs.y << 16)) + blo.z, 0.f);
    o0.w = fmaxf(di * (acc[3] + __uint_as_float(hs.y & 0xFFFF0000u)) + blo.w, 0.f);
    o1.x = fmaxf(di * (acc[4] + __uint_as_float(hs.z << 16)) + bhi.x, 0.f);
    o1.y = fmaxf(di * (acc[5] + __uint_as_float(hs.z & 0xFFFF0000u)) + bhi.y, 0.f);
    o1.z = fmaxf(di * (acc[6] + __uint_as_float(hs.w << 16)) + bhi.z, 0.f);
    o1.w = fmaxf(di * (acc[7] + __uint_as_float(hs.w & 0xFFFF0000u)) + bhi.w, 0.f);
    ((float4*)Xout)[node * 16 + 2 * i] = o0;
    ((float4*)Xout)[node * 16 + 2 * i + 1] = o1;
  }
}

// ---- layer 3: aggregate + fused mean-pool accumulate ------------------------
__global__ void agg_pool_kernel(const unsigned* __restrict__ Hs2, const int* __restrict__ cnt,
                                const int* __restrict__ csr, const int* __restrict__ ovf,
                                const int* __restrict__ ovf_cnt, const float* __restrict__ b,
                                const int* __restrict__ batch,
                                float* __restrict__ sums, float* __restrict__ cnts) {
  __shared__ float rows[4][64];
  __shared__ int gid[4];
  int stripe = blockIdx.x & (STRIPES - 1);
  int w = threadIdx.x >> 6;
  int node = stripe * NPS + (blockIdx.x >> 3) * 4 + w;
  int lane = threadIdx.x & 63;
  int g = lane >> 3, i = lane & 7;
  int c = cnt[node];
  int m = min(c, K);
  int sv = (lane < m) ? csr[node * K + lane] : node;
  float acc[8];
  gather_rows(Hs2, node, m, g, i, sv, ovf, min(*ovf_cnt, OVF_CAP), acc);
  if (lane == 0) gid[w] = batch[node];
  if (g == 0) {
    uint4 hs = ((const uint4*)Hs2)[node * 8 + i];
    float di = rsqrtf((float)c + 1.0f);
    const float4* b4 = (const float4*)b;
    float4 blo = b4[2 * i], bhi = b4[2 * i + 1];
    float4 o0, o1;
    o0.x = fmaxf(di * (acc[0] + __uint_as_float(hs.x << 16)) + blo.x, 0.f);
    o0.y = fmaxf(di * (acc[1] + __uint_as_float(hs.x & 0xFFFF0000u)) + blo.y, 0.f);
    o0.z = fmaxf(di * (acc[2] + __uint_as_float(hs.y << 16)) + blo.z, 0.f);
    o0.w = fmaxf(di * (acc[3] + __uint_as_float(hs.y & 0xFFFF0000u)) + blo.w, 0.f);
    o1.x = fmaxf(di * (acc[4] + __uint_as_float(hs.z << 16)) + bhi.x, 0.f);
    o1.y = fmaxf(di * (acc[5] + __uint_as_float(hs.z & 0xFFFF0000u)) + bhi.y, 0.f);
    o1.z = fmaxf(di * (acc[6] + __uint_as_float(hs.w << 16)) + bhi.z, 0.f);
    o1.w = fmaxf(di * (acc[7] + __uint_as_float(hs.w & 0xFFFF0000u)) + bhi.w, 0.f);
    *((float4*)&rows[w][8 * i]) = o0;
    *((float4*)&rows[w][8 * i + 4]) = o1;
  }
  __syncthreads();
  if (threadIdx.x < 64) {                      // wave 0 flushes (batch sorted)
    int cur = gid[0], run = 0;
    float s = 0.f;
    for (int ww = 0; ww < 4; ww++) {
      if (gid[ww] != cur) {
        atomicAdd(&sums[cur * 64 + lane], s);
        if (lane == 0) atomicAdd(&cnts[cur], (float)run);
        cur = gid[ww]; s = 0.f; run = 0;
      }
      s += rows[ww][lane];
      run++;
    }
    atomicAdd(&sums[cur * 64 + lane], s);
    if (lane == 0) atomicAdd(&cnts[cur], (float)run);
  }
}

__global__ void classifier_kernel(const float* __restrict__ sums, const float* __restrict__ cnts,
                                  const float* __restrict__ Wc1, const float* __restrict__ bc1,
                                  const float* __restrict__ Wc2, const float* __restrict__ bc2,
                                  float* __restrict__ out) {
  __shared__ float pooled[64 * 64];
  __shared__ float z[64 * 32];
  int tid = threadIdx.x;
  for (int idx = tid; idx < 64 * 64; idx += 256) {
    int g = idx >> 6;
    pooled[idx] = sums[idx] / fmaxf(cnts[g], 1.0f);
  }
  __syncthreads();
  for (int idx = tid; idx < 64 * 32; idx += 256) {
    int g = idx >> 5, j = idx & 31;
    float acc = bc1[j];
#pragma unroll
    for (int c = 0; c < 64; c++) acc += pooled[g * 64 + c] * Wc1[c * 32 + j];
    z[idx] = fmaxf(acc, 0.f);
  }
  __syncthreads();
  for (int idx = tid; idx < 128; idx += 256) {
    int g = idx >> 1, k = idx & 1;
    float acc = bc2[k];
#pragma unroll
    for (int j = 0; j < 32; j++) acc += z[g * 32 + j] * Wc2[j * 2 + k];
    out[idx] = acc;
  }
}

// ---- launch ----------------------------------------------------------------
extern "C" void kernel_launch(void* const* d_in, const int* in_sizes, int n_in,
                              void* d_out, int out_size, void* d_ws, size_t ws_size,
                              hipStream_t stream) {
  const float* x   = (const float*)d_in[0];
  const float* W1  = (const float*)d_in[1];
  const float* b1  = (const float*)d_in[2];
  const float* W2  = (const float*)d_in[3];
  const float* b2  = (const float*)d_in[4];
  const float* W3  = (const float*)d_in[5];
  const float* b3  = (const float*)d_in[6];
  const float* Wc1 = (const float*)d_in[7];
  const float* bc1 = (const float*)d_in[8];
  const float* Wc2 = (const float*)d_in[9];
  const float* bc2 = (const float*)d_in[10];
  const int* ei    = (const int*)d_in[11];
  const int* batch = (const int*)d_in[12];
  const int* src  = ei;
  const int* dstp = ei + E;

  char* ws = (char*)d_ws;
  size_t off = 0;
  auto alloc = [&](size_t bytes) {
    char* p = ws + off;
    off += (bytes + 255) & ~size_t(255);
    return p;
  };
  int*      cnt  = (int*)alloc((size_t)(N + 1 + STRIPES) * 4); // + ovf_cnt + workctr
  int*      csr  = (int*)alloc((size_t)N * K * 4);             // 12.8 MB
  int*      ovf  = (int*)alloc((size_t)OVF_CAP * 2 * 4);
  unsigned* Hs   = (unsigned*)alloc((size_t)N * 64 * 2);       // bf16
  float*    B1   = (float*)alloc((size_t)N * 64 * 4);
  float*    sums = (float*)alloc((size_t)(G * 64 + G) * 4);
  float*    cnts = sums + G * 64;
  int*      ovf_cnt = cnt + N;
  int*      workctr = cnt + N + 1;

  (void)hipMemsetAsync(cnt, 0, (size_t)(N + 1 + STRIPES) * 4, stream);
  (void)hipMemsetAsync(sums, 0, (size_t)(G * 64 + G) * 4, stream);

  build_kernel<<<2048, 256, 0, stream>>>(src, dstp, cnt, csr, ovf, ovf_cnt, workctr);

  // layer 1
  gemm_premul_kernel<<<N / 32, 256, 0, stream>>>(x, W1, cnt, Hs);
  agg_kernel<<<(NPS / 4) * STRIPES, 256, 0, stream>>>(Hs, cnt, csr, ovf, ovf_cnt, b1, B1);
  // layer 2
  gemm_premul_kernel<<<N / 32, 256, 0, stream>>>(B1, W2, cnt, Hs);
  agg_kernel<<<(NPS / 4) * STRIPES, 256, 0, stream>>>(Hs, cnt, csr, ovf, ovf_cnt, b2, B1);
  // layer 3 + fused pool
  gemm_premul_kernel<<<N / 32, 256, 0, stream>>>(B1, W3, cnt, Hs);
  agg_pool_kernel<<<(NPS / 4) * STRIPES, 256, 0, stream>>>(Hs, cnt, csr, ovf, ovf_cnt, b3,
                                                           batch, sums, cnts);

  classifier_kernel<<<1, 256, 0, stream>>>(sums, cnts, Wc1, bc1, Wc2, bc2, (float*)d_out);
}

// Round 11
// 458.307 us; speedup vs baseline: 1.4688x; 1.4688x over previous
//
#include <hip/hip_runtime.h>

// GCN, bf16 Hs intermediate.
// Build: static XCD-striped bucket CSR (stripe = blockIdx&7, round-7 form) with
// NONTEMPORAL edge-stream loads so the 10MB/stripe edge stream doesn't thrash
// the csr/cnt window out of L2 (thrash = write-amplification theory).
// 3x (X@W premul dinv -> bf16; pull-aggregate uint4 gathers); layer 3 fuses the
// mean-pool. Then classifier MLP.
constexpr int N = 100000;
constexpr int E = 1250000;
constexpr int G = 64;
constexpr int K = 32;            // bucket cap; P(deg>32)*N ~ 0.1, exact ovf path
constexpr int OVF_CAP = 65536;
constexpr int STRIPES = 8;
constexpr int NPS = N / STRIPES;              // 12500 nodes per stripe
constexpr int CHUNK = 10240;                  // edges per block
constexpr int CPB = (E + CHUNK - 1) / CHUNK;  // 123 chunks

typedef int iv4 __attribute__((ext_vector_type(4)));  // clang vector (NT-load ok)

__device__ inline unsigned bf16pack(float a, float b) {  // RNE, low=a high=b
  unsigned ua = __float_as_uint(a);
  ua = (ua + 0x7FFF + ((ua >> 16) & 1)) >> 16;
  unsigned ub = __float_as_uint(b);
  ub = (ub + 0x7FFF + ((ub >> 16) & 1)) & 0xFFFF0000u;
  return ua | ub;
}

// ---- static XCD-striped build, NT edge loads --------------------------------
__global__ void build_kernel(const int* __restrict__ src, const int* __restrict__ dst,
                             int* __restrict__ cnt, int* __restrict__ csr,
                             int* __restrict__ ovf, int* __restrict__ ovf_cnt) {
  int stripe = blockIdx.x & (STRIPES - 1);
  int chunk = blockIdx.x >> 3;
  int lo = stripe * NPS, hi = lo + NPS;
  int base = chunk * CHUNK + threadIdx.x * 4;
  auto process = [&](int s, int d) {
    if (d >= lo && d < hi) {
      int slot = atomicAdd(&cnt[d], 1);
      if (slot < K) {
        csr[d * K + slot] = s;
      } else {
        int q = atomicAdd(ovf_cnt, 1);
        if (q < OVF_CAP) { ovf[2 * q] = s; ovf[2 * q + 1] = d; }
      }
    }
  };
#pragma unroll 1
  for (int it = 0; it < CHUNK / 1024; it++, base += 1024) {
    if (base + 3 < E) {
      iv4 s4 = __builtin_nontemporal_load((const iv4*)(src + base));
      iv4 d4 = __builtin_nontemporal_load((const iv4*)(dst + base));
      process(s4.x, d4.x); process(s4.y, d4.y);
      process(s4.z, d4.z); process(s4.w, d4.w);
    } else {
      for (int j = 0; j < 4; j++)
        if (base + j < E) process(src[base + j], dst[base + j]);
    }
  }
}

// ---- Hs(bf16) = (X @ W) * dinv[row], 32 rows/block -------------------------
constexpr int XS_STRIDE = 68;
__global__ void gemm_premul_kernel(const float* __restrict__ X, const float* __restrict__ W,
                                   const int* __restrict__ cnt, unsigned* __restrict__ Hs2) {
  __shared__ float Ws[64 * 64];
  __shared__ float Xs[32 * XS_STRIDE];
  int tid = threadIdx.x;
  const float4* W4 = (const float4*)W;
#pragma unroll
  for (int j = 0; j < 4; j++)
    ((float4*)Ws)[tid + j * 256] = W4[tid + j * 256];
  int row0 = blockIdx.x * 32;
  const float4* X4 = (const float4*)(X + row0 * 64);
#pragma unroll
  for (int j = 0; j < 2; j++) {
    int idx = tid + j * 256;
    int r = idx >> 4, q = idx & 15;
    *((float4*)&Xs[r * XS_STRIDE + q * 4]) = X4[idx];
  }
  __syncthreads();
  int r0 = tid >> 4;
  int c = (tid & 15) * 4;
  float4 acc0 = {0, 0, 0, 0}, acc1 = {0, 0, 0, 0};
#pragma unroll
  for (int k = 0; k < 64; k++) {
    float4 w = *((const float4*)&Ws[k * 64 + c]);
    float xa = Xs[r0 * XS_STRIDE + k];
    float xb = Xs[(r0 + 16) * XS_STRIDE + k];
    acc0.x += xa * w.x; acc0.y += xa * w.y; acc0.z += xa * w.z; acc0.w += xa * w.w;
    acc1.x += xb * w.x; acc1.y += xb * w.y; acc1.z += xb * w.z; acc1.w += xb * w.w;
  }
  int ra = row0 + r0, rb = ra + 16;
  float da = rsqrtf((float)cnt[ra] + 1.0f);
  float db = rsqrtf((float)cnt[rb] + 1.0f);
  uint2 pa = make_uint2(bf16pack(acc0.x * da, acc0.y * da), bf16pack(acc0.z * da, acc0.w * da));
  uint2 pb = make_uint2(bf16pack(acc1.x * db, acc1.y * db), bf16pack(acc1.z * db, acc1.w * db));
  ((uint2*)Hs2)[ra * 16 + (tid & 15)] = pa;
  ((uint2*)Hs2)[rb * 16 + (tid & 15)] = pb;
}

// Shared gather core: acc[0..7] hold full channel sums after butterfly.
// lane = 8*g + i; group g handles edge k+g, lane covers bf16 channels 8i..8i+7.
__device__ inline void gather_rows(const unsigned* __restrict__ Hs2, int node, int m,
                                   int g, int i, int sv,
                                   const int* __restrict__ ovf, int on,
                                   float acc[8]) {
  const uint4* H4 = (const uint4*)Hs2;
#pragma unroll
  for (int t = 0; t < 8; t++) acc[t] = 0.f;
  for (int k = 0; k < m; k += 8) {
    int j = k + g;
    int s = __shfl(sv, j);
    bool valid = j < m;
    uint4 h = H4[(valid ? s : node) * 8 + i];
    if (valid) {
      acc[0] += __uint_as_float(h.x << 16); acc[1] += __uint_as_float(h.x & 0xFFFF0000u);
      acc[2] += __uint_as_float(h.y << 16); acc[3] += __uint_as_float(h.y & 0xFFFF0000u);
      acc[4] += __uint_as_float(h.z << 16); acc[5] += __uint_as_float(h.z & 0xFFFF0000u);
      acc[6] += __uint_as_float(h.w << 16); acc[7] += __uint_as_float(h.w & 0xFFFF0000u);
    }
  }
  if (on > 0 && g == 0) {                  // exact rare path (deg > K)
    for (int j = 0; j < on; j++)
      if (ovf[2 * j + 1] == node) {
        uint4 h = H4[ovf[2 * j] * 8 + i];
        acc[0] += __uint_as_float(h.x << 16); acc[1] += __uint_as_float(h.x & 0xFFFF0000u);
        acc[2] += __uint_as_float(h.y << 16); acc[3] += __uint_as_float(h.y & 0xFFFF0000u);
        acc[4] += __uint_as_float(h.z << 16); acc[5] += __uint_as_float(h.z & 0xFFFF0000u);
        acc[6] += __uint_as_float(h.w << 16); acc[7] += __uint_as_float(h.w & 0xFFFF0000u);
      }
  }
#pragma unroll
  for (int off = 8; off < 64; off <<= 1) {
#pragma unroll
    for (int t = 0; t < 8; t++) acc[t] += __shfl_xor(acc[t], off);
  }
}

// ---- layers 1,2: aggregate -> fp32 Xout ------------------------------------
__global__ void agg_kernel(const unsigned* __restrict__ Hs2, const int* __restrict__ cnt,
                           const int* __restrict__ csr, const int* __restrict__ ovf,
                           const int* __restrict__ ovf_cnt, const float* __restrict__ b,
                           float* __restrict__ Xout) {
  int stripe = blockIdx.x & (STRIPES - 1);
  int node = stripe * NPS + (blockIdx.x >> 3) * 4 + (threadIdx.x >> 6);
  int lane = threadIdx.x & 63;
  int g = lane >> 3, i = lane & 7;
  int c = cnt[node];
  int m = min(c, K);
  int sv = (lane < m) ? csr[node * K + lane] : node;
  float acc[8];
  gather_rows(Hs2, node, m, g, i, sv, ovf, min(*ovf_cnt, OVF_CAP), acc);
  if (g == 0) {
    uint4 hs = ((const uint4*)Hs2)[node * 8 + i];
    float di = rsqrtf((float)c + 1.0f);
    const float4* b4 = (const float4*)b;
    float4 blo = b4[2 * i], bhi = b4[2 * i + 1];
    float4 o0, o1;
    o0.x = fmaxf(di * (acc[0] + __uint_as_float(hs.x << 16)) + blo.x, 0.f);
    o0.y = fmaxf(di * (acc[1] + __uint_as_float(hs.x & 0xFFFF0000u)) + blo.y, 0.f);
    o0.z = fmaxf(di * (acc[2] + __uint_as_float(hs.y << 16)) + blo.z, 0.f);
    o0.w = fmaxf(di * (acc[3] + __uint_as_float(hs.y & 0xFFFF0000u)) + blo.w, 0.f);
    o1.x = fmaxf(di * (acc[4] + __uint_as_float(hs.z << 16)) + bhi.x, 0.f);
    o1.y = fmaxf(di * (acc[5] + __uint_as_float(hs.z & 0xFFFF0000u)) + bhi.y, 0.f);
    o1.z = fmaxf(di * (acc[6] + __uint_as_float(hs.w << 16)) + bhi.z, 0.f);
    o1.w = fmaxf(di * (acc[7] + __uint_as_float(hs.w & 0xFFFF0000u)) + bhi.w, 0.f);
    ((float4*)Xout)[node * 16 + 2 * i] = o0;
    ((float4*)Xout)[node * 16 + 2 * i + 1] = o1;
  }
}

// ---- layer 3: aggregate + fused mean-pool accumulate ------------------------
__global__ void agg_pool_kernel(const unsigned* __restrict__ Hs2, const int* __restrict__ cnt,
                                const int* __restrict__ csr, const int* __restrict__ ovf,
                                const int* __restrict__ ovf_cnt, const float* __restrict__ b,
                                const int* __restrict__ batch,
                                float* __restrict__ sums, float* __restrict__ cnts) {
  __shared__ float rows[4][64];
  __shared__ int gid[4];
  int stripe = blockIdx.x & (STRIPES - 1);
  int w = threadIdx.x >> 6;
  int node = stripe * NPS + (blockIdx.x >> 3) * 4 + w;
  int lane = threadIdx.x & 63;
  int g = lane >> 3, i = lane & 7;
  int c = cnt[node];
  int m = min(c, K);
  int sv = (lane < m) ? csr[node * K + lane] : node;
  float acc[8];
  gather_rows(Hs2, node, m, g, i, sv, ovf, min(*ovf_cnt, OVF_CAP), acc);
  if (lane == 0) gid[w] = batch[node];
  if (g == 0) {
    uint4 hs = ((const uint4*)Hs2)[node * 8 + i];
    float di = rsqrtf((float)c + 1.0f);
    const float4* b4 = (const float4*)b;
    float4 blo = b4[2 * i], bhi = b4[2 * i + 1];
    float4 o0, o1;
    o0.x = fmaxf(di * (acc[0] + __uint_as_float(hs.x << 16)) + blo.x, 0.f);
    o0.y = fmaxf(di * (acc[1] + __uint_as_float(hs.x & 0xFFFF0000u)) + blo.y, 0.f);
    o0.z = fmaxf(di * (acc[2] + __uint_as_float(hs.y << 16)) + blo.z, 0.f);
    o0.w = fmaxf(di * (acc[3] + __uint_as_float(hs.y & 0xFFFF0000u)) + blo.w, 0.f);
    o1.x = fmaxf(di * (acc[4] + __uint_as_float(hs.z << 16)) + bhi.x, 0.f);
    o1.y = fmaxf(di * (acc[5] + __uint_as_float(hs.z & 0xFFFF0000u)) + bhi.y, 0.f);
    o1.z = fmaxf(di * (acc[6] + __uint_as_float(hs.w << 16)) + bhi.z, 0.f);
    o1.w = fmaxf(di * (acc[7] + __uint_as_float(hs.w & 0xFFFF0000u)) + bhi.w, 0.f);
    *((float4*)&rows[w][8 * i]) = o0;
    *((float4*)&rows[w][8 * i + 4]) = o1;
  }
  __syncthreads();
  if (threadIdx.x < 64) {                      // wave 0 flushes (batch sorted)
    int cur = gid[0], run = 0;
    float s = 0.f;
    for (int ww = 0; ww < 4; ww++) {
      if (gid[ww] != cur) {
        atomicAdd(&sums[cur * 64 + lane], s);
        if (lane == 0) atomicAdd(&cnts[cur], (float)run);
        cur = gid[ww]; s = 0.f; run = 0;
      }
      s += rows[ww][lane];
      run++;
    }
    atomicAdd(&sums[cur * 64 + lane], s);
    if (lane == 0) atomicAdd(&cnts[cur], (float)run);
  }
}

__global__ void classifier_kernel(const float* __restrict__ sums, const float* __restrict__ cnts,
                                  const float* __restrict__ Wc1, const float* __restrict__ bc1,
                                  const float* __restrict__ Wc2, const float* __restrict__ bc2,
                                  float* __restrict__ out) {
  __shared__ float pooled[64 * 64];
  __shared__ float z[64 * 32];
  int tid = threadIdx.x;
  for (int idx = tid; idx < 64 * 64; idx += 256) {
    int g = idx >> 6;
    pooled[idx] = sums[idx] / fmaxf(cnts[g], 1.0f);
  }
  __syncthreads();
  for (int idx = tid; idx < 64 * 32; idx += 256) {
    int g = idx >> 5, j = idx & 31;
    float acc = bc1[j];
#pragma unroll
    for (int c = 0; c < 64; c++) acc += pooled[g * 64 + c] * Wc1[c * 32 + j];
    z[idx] = fmaxf(acc, 0.f);
  }
  __syncthreads();
  for (int idx = tid; idx < 128; idx += 256) {
    int g = idx >> 1, k = idx & 1;
    float acc = bc2[k];
#pragma unroll
    for (int j = 0; j < 32; j++) acc += z[g * 32 + j] * Wc2[j * 2 + k];
    out[idx] = acc;
  }
}

// ---- launch ----------------------------------------------------------------
extern "C" void kernel_launch(void* const* d_in, const int* in_sizes, int n_in,
                              void* d_out, int out_size, void* d_ws, size_t ws_size,
                              hipStream_t stream) {
  const float* x   = (const float*)d_in[0];
  const float* W1  = (const float*)d_in[1];
  const float* b1  = (const float*)d_in[2];
  const float* W2  = (const float*)d_in[3];
  const float* b2  = (const float*)d_in[4];
  const float* W3  = (const float*)d_in[5];
  const float* b3  = (const float*)d_in[6];
  const float* Wc1 = (const float*)d_in[7];
  const float* bc1 = (const float*)d_in[8];
  const float* Wc2 = (const float*)d_in[9];
  const float* bc2 = (const float*)d_in[10];
  const int* ei    = (const int*)d_in[11];
  const int* batch = (const int*)d_in[12];
  const int* src  = ei;
  const int* dstp = ei + E;

  char* ws = (char*)d_ws;
  size_t off = 0;
  auto alloc = [&](size_t bytes) {
    char* p = ws + off;
    off += (bytes + 255) & ~size_t(255);
    return p;
  };
  int*      cnt  = (int*)alloc((size_t)(N + 1) * 4);
  int*      csr  = (int*)alloc((size_t)N * K * 4);          // 12.8 MB
  int*      ovf  = (int*)alloc((size_t)OVF_CAP * 2 * 4);
  unsigned* Hs   = (unsigned*)alloc((size_t)N * 64 * 2);    // bf16
  float*    B1   = (float*)alloc((size_t)N * 64 * 4);
  float*    sums = (float*)alloc((size_t)(G * 64 + G) * 4);
  float*    cnts = sums + G * 64;
  int*      ovf_cnt = cnt + N;

  (void)hipMemsetAsync(cnt, 0, (size_t)(N + 1) * 4, stream);
  (void)hipMemsetAsync(sums, 0, (size_t)(G * 64 + G) * 4, stream);

  build_kernel<<<CPB * STRIPES, 256, 0, stream>>>(src, dstp, cnt, csr, ovf, ovf_cnt);

  // layer 1
  gemm_premul_kernel<<<N / 32, 256, 0, stream>>>(x, W1, cnt, Hs);
  agg_kernel<<<(NPS / 4) * STRIPES, 256, 0, stream>>>(Hs, cnt, csr, ovf, ovf_cnt, b1, B1);
  // layer 2
  gemm_premul_kernel<<<N / 32, 256, 0, stream>>>(B1, W2, cnt, Hs);
  agg_kernel<<<(NPS / 4) * STRIPES, 256, 0, stream>>>(Hs, cnt, csr, ovf, ovf_cnt, b2, B1);
  // layer 3 + fused pool
  gemm_premul_kernel<<<N / 32, 256, 0, stream>>>(B1, W3, cnt, Hs);
  agg_pool_kernel<<<(NPS / 4) * STRIPES, 256, 0, stream>>>(Hs, cnt, csr, ovf, ovf_cnt, b3,
                                                           batch, sums, cnts);

  classifier_kernel<<<1, 256, 0, stream>>>(sums, cnts, Wc1, bc1, Wc2, bc2, (float*)d_out);
}

// Round 12
// 370.513 us; speedup vs baseline: 1.8169x; 1.2370x over previous
//
#include <hip/hip_runtime.h>

// GCN, bf16 Hs intermediate.
// Build: static XCD-striped bucket CSR (stripe = blockIdx&7) with nontemporal
// edge-stream loads (L2-thrash mitigation test).
// 3x (X@W premul dinv -> bf16; pull-aggregate uint4 gathers) -> standalone
// mean-pool (wave-scans-contiguous-nodes: low atomic count) -> classifier MLP.
constexpr int N = 100000;
constexpr int E = 1250000;
constexpr int G = 64;
constexpr int K = 32;            // bucket cap; P(deg>32)*N ~ 0.1, exact ovf path
constexpr int OVF_CAP = 65536;
constexpr int STRIPES = 8;
constexpr int NPS = N / STRIPES;              // 12500 nodes per stripe
constexpr int CHUNK = 10240;                  // edges per block
constexpr int CPB = (E + CHUNK - 1) / CHUNK;  // 123 chunks

typedef int iv4 __attribute__((ext_vector_type(4)));  // clang vector (NT-load ok)

__device__ inline unsigned bf16pack(float a, float b) {  // RNE, low=a high=b
  unsigned ua = __float_as_uint(a);
  ua = (ua + 0x7FFF + ((ua >> 16) & 1)) >> 16;
  unsigned ub = __float_as_uint(b);
  ub = (ub + 0x7FFF + ((ub >> 16) & 1)) & 0xFFFF0000u;
  return ua | ub;
}

// ---- static XCD-striped build, NT edge loads --------------------------------
__global__ void build_kernel(const int* __restrict__ src, const int* __restrict__ dst,
                             int* __restrict__ cnt, int* __restrict__ csr,
                             int* __restrict__ ovf, int* __restrict__ ovf_cnt) {
  int stripe = blockIdx.x & (STRIPES - 1);
  int chunk = blockIdx.x >> 3;
  int lo = stripe * NPS, hi = lo + NPS;
  int base = chunk * CHUNK + threadIdx.x * 4;
  auto process = [&](int s, int d) {
    if (d >= lo && d < hi) {
      int slot = atomicAdd(&cnt[d], 1);
      if (slot < K) {
        csr[d * K + slot] = s;
      } else {
        int q = atomicAdd(ovf_cnt, 1);
        if (q < OVF_CAP) { ovf[2 * q] = s; ovf[2 * q + 1] = d; }
      }
    }
  };
#pragma unroll 1
  for (int it = 0; it < CHUNK / 1024; it++, base += 1024) {
    if (base + 3 < E) {
      iv4 s4 = __builtin_nontemporal_load((const iv4*)(src + base));
      iv4 d4 = __builtin_nontemporal_load((const iv4*)(dst + base));
      process(s4.x, d4.x); process(s4.y, d4.y);
      process(s4.z, d4.z); process(s4.w, d4.w);
    } else {
      for (int j = 0; j < 4; j++)
        if (base + j < E) process(src[base + j], dst[base + j]);
    }
  }
}

// ---- Hs(bf16) = (X @ W) * dinv[row], 32 rows/block -------------------------
constexpr int XS_STRIDE = 68;
__global__ void gemm_premul_kernel(const float* __restrict__ X, const float* __restrict__ W,
                                   const int* __restrict__ cnt, unsigned* __restrict__ Hs2) {
  __shared__ float Ws[64 * 64];
  __shared__ float Xs[32 * XS_STRIDE];
  int tid = threadIdx.x;
  const float4* W4 = (const float4*)W;
#pragma unroll
  for (int j = 0; j < 4; j++)
    ((float4*)Ws)[tid + j * 256] = W4[tid + j * 256];
  int row0 = blockIdx.x * 32;
  const float4* X4 = (const float4*)(X + row0 * 64);
#pragma unroll
  for (int j = 0; j < 2; j++) {
    int idx = tid + j * 256;
    int r = idx >> 4, q = idx & 15;
    *((float4*)&Xs[r * XS_STRIDE + q * 4]) = X4[idx];
  }
  __syncthreads();
  int r0 = tid >> 4;
  int c = (tid & 15) * 4;
  float4 acc0 = {0, 0, 0, 0}, acc1 = {0, 0, 0, 0};
#pragma unroll
  for (int k = 0; k < 64; k++) {
    float4 w = *((const float4*)&Ws[k * 64 + c]);
    float xa = Xs[r0 * XS_STRIDE + k];
    float xb = Xs[(r0 + 16) * XS_STRIDE + k];
    acc0.x += xa * w.x; acc0.y += xa * w.y; acc0.z += xa * w.z; acc0.w += xa * w.w;
    acc1.x += xb * w.x; acc1.y += xb * w.y; acc1.z += xb * w.z; acc1.w += xb * w.w;
  }
  int ra = row0 + r0, rb = ra + 16;
  float da = rsqrtf((float)cnt[ra] + 1.0f);
  float db = rsqrtf((float)cnt[rb] + 1.0f);
  uint2 pa = make_uint2(bf16pack(acc0.x * da, acc0.y * da), bf16pack(acc0.z * da, acc0.w * da));
  uint2 pb = make_uint2(bf16pack(acc1.x * db, acc1.y * db), bf16pack(acc1.z * db, acc1.w * db));
  ((uint2*)Hs2)[ra * 16 + (tid & 15)] = pa;
  ((uint2*)Hs2)[rb * 16 + (tid & 15)] = pb;
}

// ---- pull aggregation: one wave/node, uint4 gathers, 8 edges in flight -----
// lane = 8*g + i; group g handles edge k+g, lane covers bf16 channels 8i..8i+7.
__global__ void agg_kernel(const unsigned* __restrict__ Hs2, const int* __restrict__ cnt,
                           const int* __restrict__ csr, const int* __restrict__ ovf,
                           const int* __restrict__ ovf_cnt, const float* __restrict__ b,
                           float* __restrict__ Xout) {
  int stripe = blockIdx.x & (STRIPES - 1);
  int node = stripe * NPS + (blockIdx.x >> 3) * 4 + (threadIdx.x >> 6);
  int lane = threadIdx.x & 63;
  int g = lane >> 3, i = lane & 7;
  int c = cnt[node];
  int m = min(c, K);
  int sv = (lane < m) ? csr[node * K + lane] : node;   // coalesced 128B bucket read
  const uint4* H4 = (const uint4*)Hs2;
  float acc0 = 0, acc1 = 0, acc2 = 0, acc3 = 0, acc4 = 0, acc5 = 0, acc6 = 0, acc7 = 0;
  for (int k = 0; k < m; k += 8) {
    int j = k + g;
    int s = __shfl(sv, j);
    bool valid = j < m;
    uint4 h = H4[(valid ? s : node) * 8 + i];
    if (valid) {
      acc0 += __uint_as_float(h.x << 16); acc1 += __uint_as_float(h.x & 0xFFFF0000u);
      acc2 += __uint_as_float(h.y << 16); acc3 += __uint_as_float(h.y & 0xFFFF0000u);
      acc4 += __uint_as_float(h.z << 16); acc5 += __uint_as_float(h.z & 0xFFFF0000u);
      acc6 += __uint_as_float(h.w << 16); acc7 += __uint_as_float(h.w & 0xFFFF0000u);
    }
  }
  int on = min(*ovf_cnt, OVF_CAP);
  if (on > 0 && g == 0) {                  // exact rare path (deg > K)
    for (int j = 0; j < on; j++)
      if (ovf[2 * j + 1] == node) {
        uint4 h = H4[ovf[2 * j] * 8 + i];
        acc0 += __uint_as_float(h.x << 16); acc1 += __uint_as_float(h.x & 0xFFFF0000u);
        acc2 += __uint_as_float(h.y << 16); acc3 += __uint_as_float(h.y & 0xFFFF0000u);
        acc4 += __uint_as_float(h.z << 16); acc5 += __uint_as_float(h.z & 0xFFFF0000u);
        acc6 += __uint_as_float(h.w << 16); acc7 += __uint_as_float(h.w & 0xFFFF0000u);
      }
  }
#pragma unroll
  for (int off = 8; off < 64; off <<= 1) {
    acc0 += __shfl_xor(acc0, off); acc1 += __shfl_xor(acc1, off);
    acc2 += __shfl_xor(acc2, off); acc3 += __shfl_xor(acc3, off);
    acc4 += __shfl_xor(acc4, off); acc5 += __shfl_xor(acc5, off);
    acc6 += __shfl_xor(acc6, off); acc7 += __shfl_xor(acc7, off);
  }
  if (g == 0) {
    uint4 hs = H4[node * 8 + i];
    float di = rsqrtf((float)c + 1.0f);
    const float4* b4 = (const float4*)b;
    float4 blo = b4[2 * i], bhi = b4[2 * i + 1];
    float4 o0, o1;
    o0.x = fmaxf(di * (acc0 + __uint_as_float(hs.x << 16)) + blo.x, 0.f);
    o0.y = fmaxf(di * (acc1 + __uint_as_float(hs.x & 0xFFFF0000u)) + blo.y, 0.f);
    o0.z = fmaxf(di * (acc2 + __uint_as_float(hs.y << 16)) + blo.z, 0.f);
    o0.w = fmaxf(di * (acc3 + __uint_as_float(hs.y & 0xFFFF0000u)) + blo.w, 0.f);
    o1.x = fmaxf(di * (acc4 + __uint_as_float(hs.z << 16)) + bhi.x, 0.f);
    o1.y = fmaxf(di * (acc5 + __uint_as_float(hs.z & 0xFFFF0000u)) + bhi.y, 0.f);
    o1.z = fmaxf(di * (acc6 + __uint_as_float(hs.w << 16)) + bhi.z, 0.f);
    o1.w = fmaxf(di * (acc7 + __uint_as_float(hs.w & 0xFFFF0000u)) + bhi.w, 0.f);
    ((float4*)Xout)[node * 16 + 2 * i] = o0;
    ((float4*)Xout)[node * 16 + 2 * i + 1] = o1;
  }
}

// ---- pool: wave scans contiguous nodes, flush on graph transition ----------
__global__ void pool_kernel(const float* __restrict__ X, const int* __restrict__ batch,
                            float* __restrict__ sums, float* __restrict__ cnts) {
  int lane = threadIdx.x & 63;
  int wid = (blockIdx.x * blockDim.x + threadIdx.x) >> 6;
  int nw = (gridDim.x * blockDim.x) >> 6;
  int per = (N + nw - 1) / nw;
  int start = wid * per;
  int end = min(start + per, N);
  float acc = 0.f, cnt = 0.f;
  int cur = -1;
  for (int n = start; n < end; n++) {
    int g = batch[n];
    if (g != cur) {
      if (cur >= 0) {
        atomicAdd(&sums[cur * 64 + lane], acc);
        if (lane == 0) atomicAdd(&cnts[cur], cnt);
      }
      cur = g; acc = 0.f; cnt = 0.f;
    }
    acc += X[n * 64 + lane];
    cnt += 1.f;
  }
  if (cur >= 0) {
    atomicAdd(&sums[cur * 64 + lane], acc);
    if (lane == 0) atomicAdd(&cnts[cur], cnt);
  }
}

__global__ void classifier_kernel(const float* __restrict__ sums, const float* __restrict__ cnts,
                                  const float* __restrict__ Wc1, const float* __restrict__ bc1,
                                  const float* __restrict__ Wc2, const float* __restrict__ bc2,
                                  float* __restrict__ out) {
  __shared__ float pooled[64 * 64];
  __shared__ float z[64 * 32];
  int tid = threadIdx.x;
  for (int idx = tid; idx < 64 * 64; idx += 256) {
    int g = idx >> 6;
    pooled[idx] = sums[idx] / fmaxf(cnts[g], 1.0f);
  }
  __syncthreads();
  for (int idx = tid; idx < 64 * 32; idx += 256) {
    int g = idx >> 5, j = idx & 31;
    float acc = bc1[j];
#pragma unroll
    for (int c = 0; c < 64; c++) acc += pooled[g * 64 + c] * Wc1[c * 32 + j];
    z[idx] = fmaxf(acc, 0.f);
  }
  __syncthreads();
  for (int idx = tid; idx < 128; idx += 256) {
    int g = idx >> 1, k = idx & 1;
    float acc = bc2[k];
#pragma unroll
    for (int j = 0; j < 32; j++) acc += z[g * 32 + j] * Wc2[j * 2 + k];
    out[idx] = acc;
  }
}

// ---- launch ----------------------------------------------------------------
extern "C" void kernel_launch(void* const* d_in, const int* in_sizes, int n_in,
                              void* d_out, int out_size, void* d_ws, size_t ws_size,
                              hipStream_t stream) {
  const float* x   = (const float*)d_in[0];
  const float* W1  = (const float*)d_in[1];
  const float* b1  = (const float*)d_in[2];
  const float* W2  = (const float*)d_in[3];
  const float* b2  = (const float*)d_in[4];
  const float* W3  = (const float*)d_in[5];
  const float* b3  = (const float*)d_in[6];
  const float* Wc1 = (const float*)d_in[7];
  const float* bc1 = (const float*)d_in[8];
  const float* Wc2 = (const float*)d_in[9];
  const float* bc2 = (const float*)d_in[10];
  const int* ei    = (const int*)d_in[11];
  const int* batch = (const int*)d_in[12];
  const int* src  = ei;
  const int* dstp = ei + E;

  char* ws = (char*)d_ws;
  size_t off = 0;
  auto alloc = [&](size_t bytes) {
    char* p = ws + off;
    off += (bytes + 255) & ~size_t(255);
    return p;
  };
  int*      cnt  = (int*)alloc((size_t)(N + 1) * 4);
  int*      csr  = (int*)alloc((size_t)N * K * 4);          // 12.8 MB
  int*      ovf  = (int*)alloc((size_t)OVF_CAP * 2 * 4);
  unsigned* Hs   = (unsigned*)alloc((size_t)N * 64 * 2);    // bf16
  float*    B1   = (float*)alloc((size_t)N * 64 * 4);
  float*    sums = (float*)alloc((size_t)(G * 64 + G) * 4);
  float*    cnts = sums + G * 64;
  int*      ovf_cnt = cnt + N;

  (void)hipMemsetAsync(cnt, 0, (size_t)(N + 1) * 4, stream);
  (void)hipMemsetAsync(sums, 0, (size_t)(G * 64 + G) * 4, stream);

  build_kernel<<<CPB * STRIPES, 256, 0, stream>>>(src, dstp, cnt, csr, ovf, ovf_cnt);

  const float* Xc = x;
  const float* Wl[3] = {W1, W2, W3};
  const float* bl[3] = {b1, b2, b3};
  for (int l = 0; l < 3; l++) {
    gemm_premul_kernel<<<N / 32, 256, 0, stream>>>(Xc, Wl[l], cnt, Hs);
    agg_kernel<<<(NPS / 4) * STRIPES, 256, 0, stream>>>(Hs, cnt, csr, ovf, ovf_cnt, bl[l], B1);
    Xc = B1;
  }

  pool_kernel<<<512, 256, 0, stream>>>(Xc, batch, sums, cnts);
  classifier_kernel<<<1, 256, 0, stream>>>(sums, cnts, Wc1, bc1, Wc2, bc2, (float*)d_out);
}